// Round 10
// baseline (282.434 us; speedup 1.0000x reference)
//
#include <hip/hip_runtime.h>
#include <math.h>

#define G 32
#define N 512
#define E 8192
#define D 256
#define KCB 2048
#define GN (G * N)  // 16384

typedef __bf16 bf16x8 __attribute__((ext_vector_type(8)));
typedef float f32x4 __attribute__((ext_vector_type(4)));

// ---------------- ws layout (bytes), all offsets 256-aligned (r7/r9 layout) ----------------
static const size_t OFF_SPOS   = 0;                                   // float [G]
static const size_t OFF_SNEG   = OFF_SPOS + 256;                      // float [G]
static const size_t OFF_BEST   = OFF_SNEG + 256;                      // u64 [GN]
static const size_t ZERO_BYTES = OFF_BEST + (size_t)GN * 8;           // ~131 KB
static const size_t OFF_NEDGE  = ZERO_BYTES;                          // int [G]
static const size_t OFF_VQPART = OFF_NEDGE + 256;                     // float [GN]
static const size_t OFF_ROWOFF = OFF_VQPART + (size_t)GN * 4;         // int [GN]
static const size_t OFF_RS_OUT = OFF_ROWOFF + (size_t)GN * 4;         // float [GN]
static const size_t OFF_RS_IN  = OFF_RS_OUT + (size_t)GN * 4;         // float [GN]
static const size_t OFF_DEG_IN = OFF_RS_IN + (size_t)GN * 4;          // int [GN]
static const size_t OFF_CSR    = OFF_DEG_IN + (size_t)GN * 4;         // int [G*E]
static const size_t OFF_ADJ    = OFF_CSR + (size_t)G * E * 4;         // uint [G*N*N/32]
static const size_t OFF_RNC    = OFF_ADJ + (size_t)G * N * N / 8;     // float [KCB]
static const size_t OFF_W1T    = OFF_RNC + (size_t)KCB * 4;           // bf16 [D*D]
static const size_t OFF_W2T    = OFF_W1T + (size_t)D * D * 2;         // bf16 [D*D]
static const size_t OFF_DWT    = OFF_W2T + (size_t)D * D * 2;         // bf16 [D*D]
static const size_t OFF_CBB    = OFF_DWT + (size_t)D * D * 2;         // bf16 [KCB*D]
static const size_t OFF_FEB    = OFF_CBB + (size_t)KCB * D * 2;       // bf16 [GN*D]
static const size_t OFF_AGGB   = OFF_FEB + (size_t)GN * D * 2;        // bf16 [GN*D]
static const size_t OFF_BF32   = OFF_AGGB + (size_t)GN * D * 2;       // float [GN*D] hf
static const size_t OFF_BCB    = OFF_BF32 + (size_t)GN * D * 4;       // bf16 [GN*D]

// ---------------- mega-setup: graph build (0..31) + W transpose (32..223) ----------------
// + codebook cast/norm (224..1247, 2 rows/block) + feats cast (1248..2271).
__global__ void __launch_bounds__(512) k_setup(
    const int* __restrict__ src, const int* __restrict__ dst,
    unsigned* __restrict__ adj, int* __restrict__ nedge, int* __restrict__ row_off_g,
    float* __restrict__ rs_in_g, float* __restrict__ rs_out_g,
    int* __restrict__ deg_in_g, int* __restrict__ csr_src,
    const float* __restrict__ W1, const float* __restrict__ W2,
    const float* __restrict__ dW, __bf16* __restrict__ W1t,
    __bf16* __restrict__ W2t, __bf16* __restrict__ dWt,
    const float* __restrict__ cb, __bf16* __restrict__ cbb, float* __restrict__ rnc,
    const float* __restrict__ feats, unsigned* __restrict__ featsb2) {
  __shared__ __align__(16) char smem[41088];
  int b = blockIdx.x, t = threadIdx.x;
  if (b < 32) {  // -------- graph build (one block per graph; LDS-local atomics) --------
    int g = b;
    unsigned* s_adj = (unsigned*)smem;                 // 32768 B
    int* s_deg_in = (int*)(smem + 32768);              // 2048 B
    int* s_deg_out = (int*)(smem + 34816);             // 2048 B
    int(*s_buf)[N] = (int(*)[N])(smem + 36864);        // 4096 B
    int* s_red = (int*)(smem + 40960);                 // 32 B
    for (int i = t; i < N * N / 32; i += 512) s_adj[i] = 0;
    s_deg_in[t] = 0;
    s_deg_out[t] = 0;
    __syncthreads();
    const int* sg = src + g * E;
    const int* dg = dst + g * E;
    int se[E / 512], de[E / 512];
    int ecount = 0;
#pragma unroll
    for (int j = 0; j < E / 512; ++j) {
      int s = sg[t + j * 512], d = dg[t + j * 512];
      se[j] = s; de[j] = d;
      atomicAdd(&s_deg_out[s], 1);
      atomicAdd(&s_deg_in[d], 1);
      if (s < d) {
        int bit = s * N + d;
        unsigned m = 1u << (bit & 31);
        unsigned old = atomicOr(&s_adj[bit >> 5], m);
        if (!(old & m)) ++ecount;
      }
    }
    __syncthreads();
    for (int off = 32; off; off >>= 1) ecount += __shfl_down(ecount, off);
    if ((t & 63) == 0) s_red[t >> 6] = ecount;
    __syncthreads();
    if (t == 0) {
      int tot = 0;
      for (int i = 0; i < 8; ++i) tot += s_red[i];
      nedge[g] = tot;
    }
    unsigned* adjg = adj + (size_t)g * (N * N / 32);
    for (int i = t; i < N * N / 32; i += 512) adjg[i] = s_adj[i];
    int own = s_deg_in[t];
    s_buf[0][t] = own;
    __syncthreads();
    int cur = 0;
    for (int off = 1; off < N; off <<= 1) {
      int v = s_buf[cur][t];
      if (t >= off) v += s_buf[cur][t - off];
      s_buf[cur ^ 1][t] = v;
      __syncthreads();
      cur ^= 1;
    }
    int roff = s_buf[cur][t] - own;
    row_off_g[g * N + t] = roff;
    deg_in_g[g * N + t] = own;
    rs_in_g[g * N + t] = rsqrtf(fmaxf((float)own, 1.0f));
    rs_out_g[g * N + t] = rsqrtf(fmaxf((float)s_deg_out[t], 1.0f));
    __syncthreads();
    s_deg_in[t] = roff;  // reuse as scatter cursor
    __syncthreads();
    int* csrg = csr_src + g * E;
#pragma unroll
    for (int j = 0; j < E / 512; ++j) {
      int slot = atomicAdd(&s_deg_in[de[j]], 1);
      csrg[slot] = se[j];
    }
  } else if (b < 224) {  // -------- weight transpose: 3 matrices x 64 32x32 tiles --------
    float(*tile)[33] = (float(*)[33])smem;
    int z = (b - 32) / 64, tt = (b - 32) % 64;
    int bx = (tt & 7) * 32, by = (tt >> 3) * 32;
    const float* in = z == 0 ? W1 : (z == 1 ? W2 : dW);
    __bf16* out = z == 0 ? W1t : (z == 1 ? W2t : dWt);
    int tx = t & 31, ty = t >> 5;  // 32 x 16
#pragma unroll
    for (int r = 0; r < 32; r += 16) tile[ty + r][tx] = in[(by + ty + r) * D + bx + tx];
    __syncthreads();
#pragma unroll
    for (int r = 0; r < 32; r += 16)
      out[(size_t)(bx + ty + r) * D + by + tx] = (__bf16)tile[tx][ty + r];
  } else if (b < 1248) {  // -------- codebook cast + inv-norms, 2 rows per block --------
    float* w = (float*)smem;  // [8]
    int row = (b - 224) * 2 + (t >> 8);
    int col = t & 255;
    float v = cb[(size_t)row * D + col];
    cbb[(size_t)row * D + col] = (__bf16)v;
    float s2 = v * v;
    for (int off = 32; off; off >>= 1) s2 += __shfl_down(s2, off);
    if ((t & 63) == 0) w[t >> 6] = s2;
    __syncthreads();
    if (t == 0) rnc[row] = rsqrtf(w[0] + w[1] + w[2] + w[3] + 1e-12f);
    if (t == 256) rnc[row] = rsqrtf(w[4] + w[5] + w[6] + w[7] + 1e-12f);
  } else {  // -------- feats fp32 -> bf16 pairs: 1024 blocks x 512 thr x 4 words --------
    int i0 = (b - 1248) * 2048 + t;
#pragma unroll
    for (int q = 0; q < 4; ++q) {
      int i = i0 + q * 512;
      float2 v = ((const float2*)feats)[i];
      union { __bf16 h[2]; unsigned u; } o;
      o.h[0] = (__bf16)v.x;
      o.h[1] = (__bf16)v.y;
      featsb2[i] = o.u;
    }
  }
}

// ---------------- graph-conv aggregation: bf16 in/out, XCD-swizzled, LDS idx preload --------
__global__ void __launch_bounds__(128) k_aggregate(
    const unsigned* __restrict__ x2, const int* __restrict__ csr_src,
    const int* __restrict__ row_off, const int* __restrict__ deg_in,
    const float* __restrict__ rs_in, const float* __restrict__ rs_out,
    unsigned* __restrict__ out2) {
  int b = blockIdx.x;
  int g = ((b & 7) << 2) | (b >> 12);  // (b&7)*4 + (b>>3)/512
  int n = (b >> 3) & 511;
  int gn = (g << 9) | n;
  int t = threadIdx.x;  // 128 feature-pairs
  int cnt = deg_in[gn];
  int base = g * E + row_off[gn];
  __shared__ int sidx[128];
  __shared__ float sw[128];
  float ax = 0.f, ay = 0.f;
  for (int c0 = 0; c0 < cnt; c0 += 128) {
    int m = min(128, cnt - c0);
    if (t < m) {
      int s = csr_src[base + c0 + t];
      sidx[t] = s;
      sw[t] = rs_out[(g << 9) | s];
    }
    __syncthreads();
    for (int j = 0; j < m; ++j) {
      int s = sidx[j];
      float w = sw[j];
      unsigned v = x2[((size_t)((g << 9) | s) << 7) + t];
      ax += __uint_as_float(v << 16) * w;
      ay += __uint_as_float(v & 0xffff0000u) * w;
    }
    __syncthreads();
  }
  float ri = rs_in[gn];
  union { __bf16 h[2]; unsigned u; } o;
  o.h[0] = (__bf16)(ax * ri);
  o.h[1] = (__bf16)(ay * ri);
  out2[((size_t)gn << 7) + t] = o.u;
}

// ---------------- bf16 MFMA core: 128x128 tile, K=256, stride 256, BT layout ----------------
__device__ __forceinline__ void gload_lds16(const __bf16* g, __bf16* s) {
  __builtin_amdgcn_global_load_lds((const __attribute__((address_space(1))) void*)g,
                                   (__attribute__((address_space(3))) void*)s, 16, 0, 0);
}

__device__ __forceinline__ void mfma_core(const __bf16* __restrict__ Abase,
                                          const __bf16* __restrict__ Bbase,
                                          __bf16* sA, __bf16* sB, f32x4 (&acc)[4][4],
                                          int tid) {
  int wave = tid >> 6, lane = tid & 63;
  int wr = (wave >> 1) * 64, wc = (wave & 1) * 64;
  int m = lane & 15, quad = lane >> 4;
  for (int k0 = 0; k0 < 256; k0 += 32) {
#pragma unroll
    for (int c2 = 0; c2 < 2; ++c2) {
      int c = wave * 2 + c2;
      int row = c * 16 + (lane >> 2);
      int col = (lane & 3) * 8;
      gload_lds16(Abase + (size_t)row * 256 + k0 + col, sA + c * 512);
      gload_lds16(Bbase + (size_t)row * 256 + k0 + col, sB + c * 512);
    }
    __syncthreads();
    bf16x8 af[4], bfr[4];
#pragma unroll
    for (int i = 0; i < 4; ++i) {
      af[i] = *(const bf16x8*)&sA[(wr + i * 16 + m) * 32 + quad * 8];
      bfr[i] = *(const bf16x8*)&sB[(wc + i * 16 + m) * 32 + quad * 8];
    }
#pragma unroll
    for (int i = 0; i < 4; ++i)
#pragma unroll
      for (int j = 0; j < 4; ++j)
        acc[i][j] = __builtin_amdgcn_mfma_f32_16x16x32_bf16(af[i], bfr[j], acc[i][j], 0, 0, 0);
    __syncthreads();
  }
}

// ---------------- GEMM + bias (+relu), fp32/bf16 stores, Ncols=256 ----------------
template <bool RELU, bool SF32, bool SBF16>
__global__ void __launch_bounds__(256) k_gemm_bf16(
    const __bf16* __restrict__ A, const __bf16* __restrict__ Bt,
    const float* __restrict__ bias, float* __restrict__ C, __bf16* __restrict__ Cb) {
  __shared__ __align__(16) __bf16 sA[4096], sB[4096];
  f32x4 acc[4][4] = {};
  int tid = threadIdx.x;
  int row0 = blockIdx.x * 128, col0 = blockIdx.y * 128;
  mfma_core(A + (size_t)row0 * 256, Bt + (size_t)col0 * 256, sA, sB, acc, tid);
  int wave = tid >> 6, lane = tid & 63;
  int wr = (wave >> 1) * 64, wc = (wave & 1) * 64, quad = lane >> 4, n16 = lane & 15;
#pragma unroll
  for (int j = 0; j < 4; ++j) {
    int col = col0 + wc + j * 16 + n16;
    float bs = bias[col];
#pragma unroll
    for (int i = 0; i < 4; ++i)
#pragma unroll
      for (int r = 0; r < 4; ++r) {
        int row = row0 + wr + i * 16 + quad * 4 + r;  // C/D: col=lane&15, row=quad*4+reg
        float v = acc[i][j][r] + bs;
        if (RELU) v = fmaxf(v, 0.f);
        if (SF32) C[(size_t)row * 256 + col] = v;
        if (SBF16) Cb[(size_t)row * 256 + col] = (__bf16)v;
      }
  }
}

// ---------------- dec1 GEMM with gathered A + fused per-row vq error (y==0 blocks) --------
__global__ void __launch_bounds__(256) k_gemm_dec1(
    const __bf16* __restrict__ cbb, const unsigned long long* __restrict__ best,
    const __bf16* __restrict__ Bt, const float* __restrict__ bias,
    __bf16* __restrict__ Cb, const float* __restrict__ cb,
    const float* __restrict__ hf, float* __restrict__ vq_part) {
  __shared__ __align__(16) __bf16 sA[4096], sB[4096];
  f32x4 acc[4][4] = {};
  int tid = threadIdx.x, wave = tid >> 6, lane = tid & 63;
  int row0 = blockIdx.x * 128, col0 = blockIdx.y * 128;
  int wr = (wave >> 1) * 64, wc = (wave & 1) * 64;
  int m = lane & 15, quad = lane >> 4;
  int c0 = wave * 2, c1 = wave * 2 + 1;
  int idx0 = (int)(0xFFFFFFFFu -
                   (unsigned)(best[row0 + c0 * 16 + (lane >> 2)] & 0xFFFFFFFFull));
  int idx1 = (int)(0xFFFFFFFFu -
                   (unsigned)(best[row0 + c1 * 16 + (lane >> 2)] & 0xFFFFFFFFull));
  const __bf16* Bbase = Bt + (size_t)col0 * 256;
  for (int k0 = 0; k0 < 256; k0 += 32) {
    int col = (lane & 3) * 8;
    gload_lds16(cbb + (size_t)idx0 * 256 + k0 + col, sA + c0 * 512);
    gload_lds16(cbb + (size_t)idx1 * 256 + k0 + col, sA + c1 * 512);
    gload_lds16(Bbase + (size_t)(c0 * 16 + (lane >> 2)) * 256 + k0 + col, sB + c0 * 512);
    gload_lds16(Bbase + (size_t)(c1 * 16 + (lane >> 2)) * 256 + k0 + col, sB + c1 * 512);
    __syncthreads();
    bf16x8 af[4], bfr[4];
#pragma unroll
    for (int i = 0; i < 4; ++i) {
      af[i] = *(const bf16x8*)&sA[(wr + i * 16 + m) * 32 + quad * 8];
      bfr[i] = *(const bf16x8*)&sB[(wc + i * 16 + m) * 32 + quad * 8];
    }
#pragma unroll
    for (int i = 0; i < 4; ++i)
#pragma unroll
      for (int j = 0; j < 4; ++j)
        acc[i][j] = __builtin_amdgcn_mfma_f32_16x16x32_bf16(af[i], bfr[j], acc[i][j], 0, 0, 0);
    __syncthreads();
  }
  int n16 = lane & 15;
#pragma unroll
  for (int j = 0; j < 4; ++j) {
    int col = col0 + wc + j * 16 + n16;
    float bs = bias[col];
#pragma unroll
    for (int i = 0; i < 4; ++i)
#pragma unroll
      for (int r = 0; r < 4; ++r) {
        int row = row0 + wr + i * 16 + quad * 4 + r;
        Cb[(size_t)row * 256 + col] = (__bf16)(acc[i][j][r] + bs);
      }
  }
  if (blockIdx.y == 0) {  // fused vq squared error: wave handles 32 rows, lane 4 cols/row
    for (int rr = wave * 32; rr < wave * 32 + 32; ++rr) {
      int row = row0 + rr;
      int ci = (int)(0xFFFFFFFFu - (unsigned)(best[row] & 0xFFFFFFFFull));
      float s2 = 0.f;
#pragma unroll
      for (int q = 0; q < 4; ++q) {
        int col = q * 64 + lane;
        float d = cb[(size_t)ci * 256 + col] - hf[(size_t)row * 256 + col];
        s2 += d * d;
      }
      for (int off = 32; off; off >>= 1) s2 += __shfl_down(s2, off);
      if (lane == 0) vq_part[row] = s2;
    }
  }
}

// ---------------- LayerNorm: bf16 pairs in place ----------------
__global__ void __launch_bounds__(128) k_layernorm(
    unsigned* __restrict__ xb2, const float* __restrict__ gamma,
    const float* __restrict__ beta) {
  int row = blockIdx.x, t = threadIdx.x;  // 128 feature-pairs
  unsigned u = xb2[row * 128 + t];
  float vx = __uint_as_float(u << 16), vy = __uint_as_float(u & 0xffff0000u);
  float s = vx + vy, s2 = vx * vx + vy * vy;
  for (int off = 32; off; off >>= 1) {
    s += __shfl_down(s, off);
    s2 += __shfl_down(s2, off);
  }
  __shared__ float w1[2], w2[2];
  if ((t & 63) == 0) { w1[t >> 6] = s; w2[t >> 6] = s2; }
  __syncthreads();
  float mu = (w1[0] + w1[1]) * (1.f / D);
  float m2 = (w2[0] + w2[1]) * (1.f / D);
  float rstd = rsqrtf(m2 - mu * mu + 1e-5f);
  float2 gm = ((const float2*)gamma)[t];
  float2 bt = ((const float2*)beta)[t];
  union { __bf16 h[2]; unsigned u; } o;
  o.h[0] = (__bf16)((vx - mu) * rstd * gm.x + bt.x);
  o.h[1] = (__bf16)((vy - mu) * rstd * gm.y + bt.y);
  xb2[row * 128 + t] = o.u;
}

// ---------------- VQ: A tile resident in LDS, 4 col-tiles per block ----------------
// grid (GN/128, KCB/512). A staged ONCE (64 KB LDS) vs 16x re-staging before;
// argmax candidates carried in registers across tiles -> 1 atomicMax/row/block.
__global__ void __launch_bounds__(256) k_vq_bf16(
    const __bf16* __restrict__ A, const __bf16* __restrict__ CBt,
    const float* __restrict__ rnc, unsigned long long* __restrict__ best) {
  __shared__ __align__(16) __bf16 sA[32768];  // full 128x256 A tile (64 KB)
  __shared__ __align__(16) __bf16 sB[4096];   // one 128x32 B chunk (8 KB)
  int tid = threadIdx.x, wave = tid >> 6, lane = tid & 63;
  int row0 = blockIdx.x * 128, colbase = blockIdx.y * 512;
  int wr = (wave >> 1) * 64, wc = (wave & 1) * 64;
  int m = lane & 15, quad = lane >> 4, n16 = lane & 15;
  const __bf16* Abase = A + (size_t)row0 * 256;
  {  // stage full A tile: 8 k-chunks x 8 row-chunks (each wave 2 row-chunks)
    int rowl = lane >> 2, coll = (lane & 3) * 8;
#pragma unroll
    for (int kc = 0; kc < 8; ++kc)
#pragma unroll
      for (int c2 = 0; c2 < 2; ++c2) {
        int c = wave * 2 + c2;
        gload_lds16(Abase + (size_t)(c * 16 + rowl) * 256 + kc * 32 + coll,
                    sA + kc * 4096 + c * 512);
      }
  }
  __syncthreads();
  unsigned long long cand[4][4];
#pragma unroll
  for (int i = 0; i < 4; ++i)
#pragma unroll
    for (int r = 0; r < 4; ++r) cand[i][r] = 0ull;
  for (int jt = 0; jt < 4; ++jt) {
    int col0 = colbase + jt * 128;
    const __bf16* Bbase = CBt + (size_t)col0 * 256;
    f32x4 acc[4][4] = {};
    for (int k0 = 0; k0 < 256; k0 += 32) {
#pragma unroll
      for (int c2 = 0; c2 < 2; ++c2) {
        int c = wave * 2 + c2;
        int row = c * 16 + (lane >> 2);
        int col = (lane & 3) * 8;
        gload_lds16(Bbase + (size_t)row * 256 + k0 + col, sB + c * 512);
      }
      __syncthreads();
      bf16x8 af[4], bfr[4];
      int kc = k0 >> 5;
#pragma unroll
      for (int i = 0; i < 4; ++i) {
        af[i] = *(const bf16x8*)&sA[kc * 4096 + (wr + i * 16 + m) * 32 + quad * 8];
        bfr[i] = *(const bf16x8*)&sB[(wc + i * 16 + m) * 32 + quad * 8];
      }
#pragma unroll
      for (int i = 0; i < 4; ++i)
#pragma unroll
        for (int j = 0; j < 4; ++j)
          acc[i][j] =
              __builtin_amdgcn_mfma_f32_16x16x32_bf16(af[i], bfr[j], acc[i][j], 0, 0, 0);
      __syncthreads();
    }
#pragma unroll
    for (int i = 0; i < 4; ++i)
#pragma unroll
      for (int j = 0; j < 4; ++j) {
        int col = col0 + wc + j * 16 + n16;
        float rc = rnc[col];
#pragma unroll
        for (int r = 0; r < 4; ++r) {
          float sim = acc[i][j][r] * rc;
          unsigned u = __float_as_uint(sim);
          u = ((int)u >= 0) ? (u | 0x80000000u) : ~u;  // order-preserving map
          unsigned long long c64 =
              ((unsigned long long)u << 32) | (0xFFFFFFFFu - (unsigned)col);
          cand[i][r] = cand[i][r] > c64 ? cand[i][r] : c64;
        }
      }
  }
#pragma unroll
  for (int i = 0; i < 4; ++i) {
#pragma unroll
    for (int off = 1; off < 16; off <<= 1)
#pragma unroll
      for (int r = 0; r < 4; ++r) {
        unsigned long long o = __shfl_xor(cand[i][r], off, 64);
        cand[i][r] = cand[i][r] > o ? cand[i][r] : o;
      }
    if (n16 == 0)
#pragma unroll
      for (int r = 0; r < 4; ++r)
        atomicMax(&best[row0 + wr + i * 16 + quad * 4 + r], cand[i][r]);
  }
}

// ---------------- edge loss: per-graph qe qe^T upper tiles, bf16 MFMA + softplus ----------
__constant__ int c_ti[10] = {0, 0, 0, 0, 1, 1, 1, 2, 2, 3};
__constant__ int c_tj[10] = {0, 1, 2, 3, 1, 2, 3, 2, 3, 3};

__global__ void __launch_bounds__(256) k_edge_bf16(
    const __bf16* __restrict__ qe, const unsigned* __restrict__ adj,
    float* __restrict__ Spos, float* __restrict__ Sneg) {
  int g = blockIdx.x / 10, p = blockIdx.x % 10;
  int row0 = c_ti[p] * 128, col0 = c_tj[p] * 128;
  const __bf16* Ag = qe + (size_t)g * N * D;
  const unsigned* adjg = adj + (size_t)g * (N * N / 32);
  __shared__ __align__(16) __bf16 sA[4096], sB[4096];
  f32x4 acc[4][4] = {};
  int tid = threadIdx.x;
  mfma_core(Ag + (size_t)row0 * 256, Ag + (size_t)col0 * 256, sA, sB, acc, tid);
  int wave = tid >> 6, lane = tid & 63;
  int wr = (wave >> 1) * 64, wc = (wave & 1) * 64, quad = lane >> 4, n16 = lane & 15;
  float spos = 0.f, sneg = 0.f;
#pragma unroll
  for (int i = 0; i < 4; ++i)
#pragma unroll
    for (int j = 0; j < 4; ++j) {
      int c = col0 + wc + j * 16 + n16;
#pragma unroll
      for (int r = 0; r < 4; ++r) {
        int rr = row0 + wr + i * 16 + quad * 4 + r;
        if (rr < c) {
          float l = acc[i][j][r];
          int bit = rr * N + c;
          bool a = (adjg[bit >> 5] >> (bit & 31)) & 1u;
          float spabs = log1pf(expf(-fabsf(l)));
          if (a) spos += fmaxf(-l, 0.f) + spabs;
          else sneg += fmaxf(l, 0.f) + spabs;
        }
      }
    }
  for (int off = 32; off; off >>= 1) {
    spos += __shfl_down(spos, off);
    sneg += __shfl_down(sneg, off);
  }
  __shared__ float wp[4], wn[4];
  if ((tid & 63) == 0) { wp[tid >> 6] = spos; wn[tid >> 6] = sneg; }
  __syncthreads();
  if (tid == 0) {
    atomicAdd(&Spos[g], wp[0] + wp[1] + wp[2] + wp[3]);
    atomicAdd(&Sneg[g], wn[0] + wn[1] + wn[2] + wn[3]);
  }
}

// ---------------- finalize ----------------
__global__ void __launch_bounds__(256) k_final(
    const int* __restrict__ nedge, const float* __restrict__ Spos,
    const float* __restrict__ Sneg, const float* __restrict__ vq_part,
    float* __restrict__ out) {
  int t = threadIdx.x;  // 256
  float vq = 0.f;
  for (int i = t; i < GN; i += 256) vq += vq_part[i];
  float el = 0.f;
  if (t < G) {
    float ne = (float)nedge[t];
    float pw = (131072.0f - ne) / (ne + 1e-6f);          // N*N/2
    el = (pw * Spos[t] + Sneg[t]) * (1.0f / 130816.0f);  // N*(N-1)/2
  }
  for (int off = 32; off; off >>= 1) {
    vq += __shfl_down(vq, off);
    el += __shfl_down(el, off);
  }
  __shared__ float wv[4], we[4];
  if ((t & 63) == 0) { wv[t >> 6] = vq; we[t >> 6] = el; }
  __syncthreads();
  if (t == 0) {
    float vqs = wv[0] + wv[1] + wv[2] + wv[3];
    float els = we[0] + we[1] + we[2] + we[3];
    out[0] = 100.0f * (els * (1.0f / G)) + 1000.0f * (vqs * (1.0f / ((float)GN * D)));
  }
}

extern "C" void kernel_launch(void* const* d_in, const int* in_sizes, int n_in,
                              void* d_out, int out_size, void* d_ws, size_t ws_size,
                              hipStream_t stream) {
  const float* feats = (const float*)d_in[0];
  const int* src = (const int*)d_in[1];
  const int* dst = (const int*)d_in[2];
  const float* W1 = (const float*)d_in[3];
  const float* b1 = (const float*)d_in[4];
  const float* W2 = (const float*)d_in[5];
  const float* b2 = (const float*)d_in[6];
  const float* ln_g = (const float*)d_in[7];
  const float* ln_b = (const float*)d_in[8];
  const float* dec1_W = (const float*)d_in[9];
  const float* dec1_b = (const float*)d_in[10];
  // d_in[11], d_in[12] = dec2 (unused: LAMB_NODE == 0)
  const float* cb = (const float*)d_in[13];

  char* ws = (char*)d_ws;
  float* Spos = (float*)(ws + OFF_SPOS);
  float* Sneg = (float*)(ws + OFF_SNEG);
  unsigned long long* best = (unsigned long long*)(ws + OFF_BEST);
  int* nedge = (int*)(ws + OFF_NEDGE);
  float* vq_part = (float*)(ws + OFF_VQPART);
  int* row_off = (int*)(ws + OFF_ROWOFF);
  float* rs_out = (float*)(ws + OFF_RS_OUT);
  float* rs_in = (float*)(ws + OFF_RS_IN);
  int* deg_in = (int*)(ws + OFF_DEG_IN);
  int* csr_src = (int*)(ws + OFF_CSR);
  unsigned* adj = (unsigned*)(ws + OFF_ADJ);
  float* rnc = (float*)(ws + OFF_RNC);
  __bf16* W1t = (__bf16*)(ws + OFF_W1T);
  __bf16* W2t = (__bf16*)(ws + OFF_W2T);
  __bf16* dWt = (__bf16*)(ws + OFF_DWT);
  __bf16* cbb = (__bf16*)(ws + OFF_CBB);
  unsigned* featsb2 = (unsigned*)(ws + OFF_FEB);
  __bf16* aggb = (__bf16*)(ws + OFF_AGGB);   // agg out (conv A); later qe
  unsigned* aggb2 = (unsigned*)(ws + OFF_AGGB);
  float* bf32 = (float*)(ws + OFF_BF32);     // hf fp32
  __bf16* bcb = (__bf16*)(ws + OFF_BCB);     // h1 (LN in place), then hf bf16
  unsigned* bcb2 = (unsigned*)(ws + OFF_BCB);

  hipMemsetAsync(d_ws, 0, ZERO_BYTES, stream);  // Spos/Sneg/best (~131 KB)

  // setup: graph build + weight transpose + codebook + feats cast, one launch
  k_setup<<<2272, 512, 0, stream>>>(src, dst, adj, nedge, row_off, rs_in, rs_out,
                                    deg_in, csr_src, W1, W2, dec1_W, W1t, W2t, dWt,
                                    cb, cbb, rnc, feats, featsb2);

  // conv1: aggregate(bf16) -> MFMA GEMM(relu, bf16 out) -> layernorm(bf16 in place)
  k_aggregate<<<GN, 128, 0, stream>>>(featsb2, csr_src, row_off, deg_in, rs_in, rs_out,
                                      aggb2);
  k_gemm_bf16<true, false, true><<<dim3(GN / 128, 2), 256, 0, stream>>>(
      aggb, W1t, b1, nullptr, bcb);
  k_layernorm<<<GN, 128, 0, stream>>>(bcb2, ln_g, ln_b);

  // conv2: aggregate(bf16) -> MFMA GEMM(relu, dual store: hf fp32 + bf16)
  k_aggregate<<<GN, 128, 0, stream>>>(bcb2, csr_src, row_off, deg_in, rs_in, rs_out, aggb2);
  k_gemm_bf16<true, true, true><<<dim3(GN / 128, 2), 256, 0, stream>>>(
      aggb, W2t, b2, bf32, bcb);

  // VQ argmax (A-resident, 4 col-tiles/block); dec1 gathers q + fused vq error
  k_vq_bf16<<<dim3(GN / 128, KCB / 512), 256, 0, stream>>>(bcb, cbb, rnc, best);
  k_gemm_dec1<<<dim3(GN / 128, 2), 256, 0, stream>>>(cbb, best, dWt, dec1_b, aggb,
                                                     cb, bf32, vq_part);
  k_edge_bf16<<<10 * G, 256, 0, stream>>>(aggb, adj, Spos, Sneg);

  k_final<<<1, 256, 0, stream>>>(nedge, Spos, Sneg, vq_part, (float*)d_out);
}

// Round 11
// 277.129 us; speedup vs baseline: 1.0191x; 1.0191x over previous
//
#include <hip/hip_runtime.h>
#include <math.h>

#define G 32
#define N 512
#define E 8192
#define D 256
#define KCB 2048
#define GN (G * N)  // 16384

typedef __bf16 bf16x8 __attribute__((ext_vector_type(8)));
typedef float f32x4 __attribute__((ext_vector_type(4)));

// ---------------- ws layout (bytes), all offsets 256-aligned (r7/r9 layout) ----------------
static const size_t OFF_SPOS   = 0;                                   // float [G]
static const size_t OFF_SNEG   = OFF_SPOS + 256;                      // float [G]
static const size_t OFF_BEST   = OFF_SNEG + 256;                      // u64 [GN]
static const size_t ZERO_BYTES = OFF_BEST + (size_t)GN * 8;           // ~131 KB
static const size_t OFF_NEDGE  = ZERO_BYTES;                          // int [G]
static const size_t OFF_VQPART = OFF_NEDGE + 256;                     // float [GN]
static const size_t OFF_ROWOFF = OFF_VQPART + (size_t)GN * 4;         // int [GN]
static const size_t OFF_RS_OUT = OFF_ROWOFF + (size_t)GN * 4;         // float [GN]
static const size_t OFF_RS_IN  = OFF_RS_OUT + (size_t)GN * 4;         // float [GN]
static const size_t OFF_DEG_IN = OFF_RS_IN + (size_t)GN * 4;          // int [GN]
static const size_t OFF_CSR    = OFF_DEG_IN + (size_t)GN * 4;         // int [G*E]
static const size_t OFF_ADJ    = OFF_CSR + (size_t)G * E * 4;         // uint [G*N*N/32]
static const size_t OFF_RNC    = OFF_ADJ + (size_t)G * N * N / 8;     // float [KCB]
static const size_t OFF_W1T    = OFF_RNC + (size_t)KCB * 4;           // bf16 [D*D]
static const size_t OFF_W2T    = OFF_W1T + (size_t)D * D * 2;         // bf16 [D*D]
static const size_t OFF_DWT    = OFF_W2T + (size_t)D * D * 2;         // bf16 [D*D]
static const size_t OFF_CBB    = OFF_DWT + (size_t)D * D * 2;         // bf16 [KCB*D]
static const size_t OFF_FEB    = OFF_CBB + (size_t)KCB * D * 2;       // bf16 [GN*D]
static const size_t OFF_AGGB   = OFF_FEB + (size_t)GN * D * 2;        // bf16 [GN*D]
static const size_t OFF_BF32   = OFF_AGGB + (size_t)GN * D * 2;       // float [GN*D] hf
static const size_t OFF_BCB    = OFF_BF32 + (size_t)GN * D * 4;       // bf16 [GN*D]

// ---------------- mega-setup: graph build (0..31) + W transpose (32..223) ----------------
// + codebook cast/norm (224..1247, 2 rows/block) + feats cast (1248..2271).
__global__ void __launch_bounds__(512) k_setup(
    const int* __restrict__ src, const int* __restrict__ dst,
    unsigned* __restrict__ adj, int* __restrict__ nedge, int* __restrict__ row_off_g,
    float* __restrict__ rs_in_g, float* __restrict__ rs_out_g,
    int* __restrict__ deg_in_g, int* __restrict__ csr_src,
    const float* __restrict__ W1, const float* __restrict__ W2,
    const float* __restrict__ dW, __bf16* __restrict__ W1t,
    __bf16* __restrict__ W2t, __bf16* __restrict__ dWt,
    const float* __restrict__ cb, __bf16* __restrict__ cbb, float* __restrict__ rnc,
    const float* __restrict__ feats, unsigned* __restrict__ featsb2) {
  __shared__ __align__(16) char smem[41088];
  int b = blockIdx.x, t = threadIdx.x;
  if (b < 32) {  // -------- graph build (one block per graph; LDS-local atomics) --------
    int g = b;
    unsigned* s_adj = (unsigned*)smem;                 // 32768 B
    int* s_deg_in = (int*)(smem + 32768);              // 2048 B
    int* s_deg_out = (int*)(smem + 34816);             // 2048 B
    int(*s_buf)[N] = (int(*)[N])(smem + 36864);        // 4096 B
    int* s_red = (int*)(smem + 40960);                 // 32 B
    for (int i = t; i < N * N / 32; i += 512) s_adj[i] = 0;
    s_deg_in[t] = 0;
    s_deg_out[t] = 0;
    __syncthreads();
    const int* sg = src + g * E;
    const int* dg = dst + g * E;
    int se[E / 512], de[E / 512];
    int ecount = 0;
#pragma unroll
    for (int j = 0; j < E / 512; ++j) {
      int s = sg[t + j * 512], d = dg[t + j * 512];
      se[j] = s; de[j] = d;
      atomicAdd(&s_deg_out[s], 1);
      atomicAdd(&s_deg_in[d], 1);
      if (s < d) {
        int bit = s * N + d;
        unsigned m = 1u << (bit & 31);
        unsigned old = atomicOr(&s_adj[bit >> 5], m);
        if (!(old & m)) ++ecount;
      }
    }
    __syncthreads();
    for (int off = 32; off; off >>= 1) ecount += __shfl_down(ecount, off);
    if ((t & 63) == 0) s_red[t >> 6] = ecount;
    __syncthreads();
    if (t == 0) {
      int tot = 0;
      for (int i = 0; i < 8; ++i) tot += s_red[i];
      nedge[g] = tot;
    }
    unsigned* adjg = adj + (size_t)g * (N * N / 32);
    for (int i = t; i < N * N / 32; i += 512) adjg[i] = s_adj[i];
    int own = s_deg_in[t];
    s_buf[0][t] = own;
    __syncthreads();
    int cur = 0;
    for (int off = 1; off < N; off <<= 1) {
      int v = s_buf[cur][t];
      if (t >= off) v += s_buf[cur][t - off];
      s_buf[cur ^ 1][t] = v;
      __syncthreads();
      cur ^= 1;
    }
    int roff = s_buf[cur][t] - own;
    row_off_g[g * N + t] = roff;
    deg_in_g[g * N + t] = own;
    rs_in_g[g * N + t] = rsqrtf(fmaxf((float)own, 1.0f));
    rs_out_g[g * N + t] = rsqrtf(fmaxf((float)s_deg_out[t], 1.0f));
    __syncthreads();
    s_deg_in[t] = roff;  // reuse as scatter cursor
    __syncthreads();
    int* csrg = csr_src + g * E;
#pragma unroll
    for (int j = 0; j < E / 512; ++j) {
      int slot = atomicAdd(&s_deg_in[de[j]], 1);
      csrg[slot] = se[j];
    }
  } else if (b < 224) {  // -------- weight transpose: 3 matrices x 64 32x32 tiles --------
    float(*tile)[33] = (float(*)[33])smem;
    int z = (b - 32) / 64, tt = (b - 32) % 64;
    int bx = (tt & 7) * 32, by = (tt >> 3) * 32;
    const float* in = z == 0 ? W1 : (z == 1 ? W2 : dW);
    __bf16* out = z == 0 ? W1t : (z == 1 ? W2t : dWt);
    int tx = t & 31, ty = t >> 5;  // 32 x 16
#pragma unroll
    for (int r = 0; r < 32; r += 16) tile[ty + r][tx] = in[(by + ty + r) * D + bx + tx];
    __syncthreads();
#pragma unroll
    for (int r = 0; r < 32; r += 16)
      out[(size_t)(bx + ty + r) * D + by + tx] = (__bf16)tile[tx][ty + r];
  } else if (b < 1248) {  // -------- codebook cast + inv-norms, 2 rows per block --------
    float* w = (float*)smem;  // [8]
    int row = (b - 224) * 2 + (t >> 8);
    int col = t & 255;
    float v = cb[(size_t)row * D + col];
    cbb[(size_t)row * D + col] = (__bf16)v;
    float s2 = v * v;
    for (int off = 32; off; off >>= 1) s2 += __shfl_down(s2, off);
    if ((t & 63) == 0) w[t >> 6] = s2;
    __syncthreads();
    if (t == 0) rnc[row] = rsqrtf(w[0] + w[1] + w[2] + w[3] + 1e-12f);
    if (t == 256) rnc[row] = rsqrtf(w[4] + w[5] + w[6] + w[7] + 1e-12f);
  } else {  // -------- feats fp32 -> bf16 pairs: 1024 blocks x 512 thr x 4 words --------
    int i0 = (b - 1248) * 2048 + t;
#pragma unroll
    for (int q = 0; q < 4; ++q) {
      int i = i0 + q * 512;
      float2 v = ((const float2*)feats)[i];
      union { __bf16 h[2]; unsigned u; } o;
      o.h[0] = (__bf16)v.x;
      o.h[1] = (__bf16)v.y;
      featsb2[i] = o.u;
    }
  }
}

// ---------------- graph-conv aggregation: bf16 in/out, XCD-swizzled, LDS idx preload --------
__global__ void __launch_bounds__(128) k_aggregate(
    const unsigned* __restrict__ x2, const int* __restrict__ csr_src,
    const int* __restrict__ row_off, const int* __restrict__ deg_in,
    const float* __restrict__ rs_in, const float* __restrict__ rs_out,
    unsigned* __restrict__ out2) {
  int b = blockIdx.x;
  int g = ((b & 7) << 2) | (b >> 12);  // (b&7)*4 + (b>>3)/512
  int n = (b >> 3) & 511;
  int gn = (g << 9) | n;
  int t = threadIdx.x;  // 128 feature-pairs
  int cnt = deg_in[gn];
  int base = g * E + row_off[gn];
  __shared__ int sidx[128];
  __shared__ float sw[128];
  float ax = 0.f, ay = 0.f;
  for (int c0 = 0; c0 < cnt; c0 += 128) {
    int m = min(128, cnt - c0);
    if (t < m) {
      int s = csr_src[base + c0 + t];
      sidx[t] = s;
      sw[t] = rs_out[(g << 9) | s];
    }
    __syncthreads();
    for (int j = 0; j < m; ++j) {
      int s = sidx[j];
      float w = sw[j];
      unsigned v = x2[((size_t)((g << 9) | s) << 7) + t];
      ax += __uint_as_float(v << 16) * w;
      ay += __uint_as_float(v & 0xffff0000u) * w;
    }
    __syncthreads();
  }
  float ri = rs_in[gn];
  union { __bf16 h[2]; unsigned u; } o;
  o.h[0] = (__bf16)(ax * ri);
  o.h[1] = (__bf16)(ay * ri);
  out2[((size_t)gn << 7) + t] = o.u;
}

// ---------------- bf16 MFMA core: 128x128 tile, K=256, stride 256, BT layout ----------------
__device__ __forceinline__ void gload_lds16(const __bf16* g, __bf16* s) {
  __builtin_amdgcn_global_load_lds((const __attribute__((address_space(1))) void*)g,
                                   (__attribute__((address_space(3))) void*)s, 16, 0, 0);
}

__device__ __forceinline__ void mfma_core(const __bf16* __restrict__ Abase,
                                          const __bf16* __restrict__ Bbase,
                                          __bf16* sA, __bf16* sB, f32x4 (&acc)[4][4],
                                          int tid) {
  int wave = tid >> 6, lane = tid & 63;
  int wr = (wave >> 1) * 64, wc = (wave & 1) * 64;
  int m = lane & 15, quad = lane >> 4;
  for (int k0 = 0; k0 < 256; k0 += 32) {
#pragma unroll
    for (int c2 = 0; c2 < 2; ++c2) {
      int c = wave * 2 + c2;
      int row = c * 16 + (lane >> 2);
      int col = (lane & 3) * 8;
      gload_lds16(Abase + (size_t)row * 256 + k0 + col, sA + c * 512);
      gload_lds16(Bbase + (size_t)row * 256 + k0 + col, sB + c * 512);
    }
    __syncthreads();
    bf16x8 af[4], bfr[4];
#pragma unroll
    for (int i = 0; i < 4; ++i) {
      af[i] = *(const bf16x8*)&sA[(wr + i * 16 + m) * 32 + quad * 8];
      bfr[i] = *(const bf16x8*)&sB[(wc + i * 16 + m) * 32 + quad * 8];
    }
#pragma unroll
    for (int i = 0; i < 4; ++i)
#pragma unroll
      for (int j = 0; j < 4; ++j)
        acc[i][j] = __builtin_amdgcn_mfma_f32_16x16x32_bf16(af[i], bfr[j], acc[i][j], 0, 0, 0);
    __syncthreads();
  }
}

// ---------------- GEMM + bias (+relu), fp32/bf16 stores, Ncols=256 ----------------
template <bool RELU, bool SF32, bool SBF16>
__global__ void __launch_bounds__(256) k_gemm_bf16(
    const __bf16* __restrict__ A, const __bf16* __restrict__ Bt,
    const float* __restrict__ bias, float* __restrict__ C, __bf16* __restrict__ Cb) {
  __shared__ __align__(16) __bf16 sA[4096], sB[4096];
  f32x4 acc[4][4] = {};
  int tid = threadIdx.x;
  int row0 = blockIdx.x * 128, col0 = blockIdx.y * 128;
  mfma_core(A + (size_t)row0 * 256, Bt + (size_t)col0 * 256, sA, sB, acc, tid);
  int wave = tid >> 6, lane = tid & 63;
  int wr = (wave >> 1) * 64, wc = (wave & 1) * 64, quad = lane >> 4, n16 = lane & 15;
#pragma unroll
  for (int j = 0; j < 4; ++j) {
    int col = col0 + wc + j * 16 + n16;
    float bs = bias[col];
#pragma unroll
    for (int i = 0; i < 4; ++i)
#pragma unroll
      for (int r = 0; r < 4; ++r) {
        int row = row0 + wr + i * 16 + quad * 4 + r;  // C/D: col=lane&15, row=quad*4+reg
        float v = acc[i][j][r] + bs;
        if (RELU) v = fmaxf(v, 0.f);
        if (SF32) C[(size_t)row * 256 + col] = v;
        if (SBF16) Cb[(size_t)row * 256 + col] = (__bf16)v;
      }
  }
}

// ---------------- dec1 GEMM with gathered A + fused per-row vq error (y==0 blocks) --------
__global__ void __launch_bounds__(256) k_gemm_dec1(
    const __bf16* __restrict__ cbb, const unsigned long long* __restrict__ best,
    const __bf16* __restrict__ Bt, const float* __restrict__ bias,
    __bf16* __restrict__ Cb, const float* __restrict__ cb,
    const float* __restrict__ hf, float* __restrict__ vq_part) {
  __shared__ __align__(16) __bf16 sA[4096], sB[4096];
  f32x4 acc[4][4] = {};
  int tid = threadIdx.x, wave = tid >> 6, lane = tid & 63;
  int row0 = blockIdx.x * 128, col0 = blockIdx.y * 128;
  int wr = (wave >> 1) * 64, wc = (wave & 1) * 64;
  int m = lane & 15, quad = lane >> 4;
  int c0 = wave * 2, c1 = wave * 2 + 1;
  int idx0 = (int)(0xFFFFFFFFu -
                   (unsigned)(best[row0 + c0 * 16 + (lane >> 2)] & 0xFFFFFFFFull));
  int idx1 = (int)(0xFFFFFFFFu -
                   (unsigned)(best[row0 + c1 * 16 + (lane >> 2)] & 0xFFFFFFFFull));
  const __bf16* Bbase = Bt + (size_t)col0 * 256;
  for (int k0 = 0; k0 < 256; k0 += 32) {
    int col = (lane & 3) * 8;
    gload_lds16(cbb + (size_t)idx0 * 256 + k0 + col, sA + c0 * 512);
    gload_lds16(cbb + (size_t)idx1 * 256 + k0 + col, sA + c1 * 512);
    gload_lds16(Bbase + (size_t)(c0 * 16 + (lane >> 2)) * 256 + k0 + col, sB + c0 * 512);
    gload_lds16(Bbase + (size_t)(c1 * 16 + (lane >> 2)) * 256 + k0 + col, sB + c1 * 512);
    __syncthreads();
    bf16x8 af[4], bfr[4];
#pragma unroll
    for (int i = 0; i < 4; ++i) {
      af[i] = *(const bf16x8*)&sA[(wr + i * 16 + m) * 32 + quad * 8];
      bfr[i] = *(const bf16x8*)&sB[(wc + i * 16 + m) * 32 + quad * 8];
    }
#pragma unroll
    for (int i = 0; i < 4; ++i)
#pragma unroll
      for (int j = 0; j < 4; ++j)
        acc[i][j] = __builtin_amdgcn_mfma_f32_16x16x32_bf16(af[i], bfr[j], acc[i][j], 0, 0, 0);
    __syncthreads();
  }
  int n16 = lane & 15;
#pragma unroll
  for (int j = 0; j < 4; ++j) {
    int col = col0 + wc + j * 16 + n16;
    float bs = bias[col];
#pragma unroll
    for (int i = 0; i < 4; ++i)
#pragma unroll
      for (int r = 0; r < 4; ++r) {
        int row = row0 + wr + i * 16 + quad * 4 + r;
        Cb[(size_t)row * 256 + col] = (__bf16)(acc[i][j][r] + bs);
      }
  }
  if (blockIdx.y == 0) {  // fused vq squared error: wave handles 32 rows, lane 4 cols/row
    for (int rr = wave * 32; rr < wave * 32 + 32; ++rr) {
      int row = row0 + rr;
      int ci = (int)(0xFFFFFFFFu - (unsigned)(best[row] & 0xFFFFFFFFull));
      float s2 = 0.f;
#pragma unroll
      for (int q = 0; q < 4; ++q) {
        int col = q * 64 + lane;
        float d = cb[(size_t)ci * 256 + col] - hf[(size_t)row * 256 + col];
        s2 += d * d;
      }
      for (int off = 32; off; off >>= 1) s2 += __shfl_down(s2, off);
      if (lane == 0) vq_part[row] = s2;
    }
  }
}

// ---------------- LayerNorm: bf16 pairs in place ----------------
__global__ void __launch_bounds__(128) k_layernorm(
    unsigned* __restrict__ xb2, const float* __restrict__ gamma,
    const float* __restrict__ beta) {
  int row = blockIdx.x, t = threadIdx.x;  // 128 feature-pairs
  unsigned u = xb2[row * 128 + t];
  float vx = __uint_as_float(u << 16), vy = __uint_as_float(u & 0xffff0000u);
  float s = vx + vy, s2 = vx * vx + vy * vy;
  for (int off = 32; off; off >>= 1) {
    s += __shfl_down(s, off);
    s2 += __shfl_down(s2, off);
  }
  __shared__ float w1[2], w2[2];
  if ((t & 63) == 0) { w1[t >> 6] = s; w2[t >> 6] = s2; }
  __syncthreads();
  float mu = (w1[0] + w1[1]) * (1.f / D);
  float m2 = (w2[0] + w2[1]) * (1.f / D);
  float rstd = rsqrtf(m2 - mu * mu + 1e-5f);
  float2 gm = ((const float2*)gamma)[t];
  float2 bt = ((const float2*)beta)[t];
  union { __bf16 h[2]; unsigned u; } o;
  o.h[0] = (__bf16)((vx - mu) * rstd * gm.x + bt.x);
  o.h[1] = (__bf16)((vy - mu) * rstd * gm.y + bt.y);
  xb2[row * 128 + t] = o.u;
}

// ---------------- VQ (r9 form): bf16 MFMA sims + packed argmax, grid (128,16) ----------
// r10's A-resident variant regressed: 72 KB LDS -> 2 blocks/CU (10% occupancy) + 8-way
// LDS bank conflicts. The 16x A re-staging is L2/L3-absorbed (FETCH 8.3 MB) — keep it.
__global__ void __launch_bounds__(256) k_vq_bf16(
    const __bf16* __restrict__ A, const __bf16* __restrict__ CBt,
    const float* __restrict__ rnc, unsigned long long* __restrict__ best) {
  __shared__ __align__(16) __bf16 sA[4096], sB[4096];
  f32x4 acc[4][4] = {};
  int tid = threadIdx.x;
  int row0 = blockIdx.x * 128, col0 = blockIdx.y * 128;
  mfma_core(A + (size_t)row0 * 256, CBt + (size_t)col0 * 256, sA, sB, acc, tid);
  int wave = tid >> 6, lane = tid & 63;
  int wr = (wave >> 1) * 64, wc = (wave & 1) * 64, quad = lane >> 4, n16 = lane & 15;
#pragma unroll
  for (int i = 0; i < 4; ++i) {
    unsigned long long cand[4] = {0ull, 0ull, 0ull, 0ull};
#pragma unroll
    for (int j = 0; j < 4; ++j) {
      int col = col0 + wc + j * 16 + n16;
      float rc = rnc[col];
#pragma unroll
      for (int r = 0; r < 4; ++r) {
        float sim = acc[i][j][r] * rc;
        unsigned u = __float_as_uint(sim);
        u = ((int)u >= 0) ? (u | 0x80000000u) : ~u;  // order-preserving map
        unsigned long long c64 =
            ((unsigned long long)u << 32) | (0xFFFFFFFFu - (unsigned)col);
        cand[r] = cand[r] > c64 ? cand[r] : c64;
      }
    }
#pragma unroll
    for (int off = 1; off < 16; off <<= 1)
#pragma unroll
      for (int r = 0; r < 4; ++r) {
        unsigned long long o = __shfl_xor(cand[r], off, 64);
        cand[r] = cand[r] > o ? cand[r] : o;
      }
    if (n16 == 0)
#pragma unroll
      for (int r = 0; r < 4; ++r)
        atomicMax(&best[row0 + wr + i * 16 + quad * 4 + r], cand[r]);
  }
}

// ---------------- edge loss: per-graph qe qe^T upper tiles, bf16 MFMA + softplus ----------
__constant__ int c_ti[10] = {0, 0, 0, 0, 1, 1, 1, 2, 2, 3};
__constant__ int c_tj[10] = {0, 1, 2, 3, 1, 2, 3, 2, 3, 3};

__global__ void __launch_bounds__(256) k_edge_bf16(
    const __bf16* __restrict__ qe, const unsigned* __restrict__ adj,
    float* __restrict__ Spos, float* __restrict__ Sneg) {
  int g = blockIdx.x / 10, p = blockIdx.x % 10;
  int row0 = c_ti[p] * 128, col0 = c_tj[p] * 128;
  const __bf16* Ag = qe + (size_t)g * N * D;
  const unsigned* adjg = adj + (size_t)g * (N * N / 32);
  __shared__ __align__(16) __bf16 sA[4096], sB[4096];
  f32x4 acc[4][4] = {};
  int tid = threadIdx.x;
  mfma_core(Ag + (size_t)row0 * 256, Ag + (size_t)col0 * 256, sA, sB, acc, tid);
  int wave = tid >> 6, lane = tid & 63;
  int wr = (wave >> 1) * 64, wc = (wave & 1) * 64, quad = lane >> 4, n16 = lane & 15;
  float spos = 0.f, sneg = 0.f;
#pragma unroll
  for (int i = 0; i < 4; ++i)
#pragma unroll
    for (int j = 0; j < 4; ++j) {
      int c = col0 + wc + j * 16 + n16;
#pragma unroll
      for (int r = 0; r < 4; ++r) {
        int rr = row0 + wr + i * 16 + quad * 4 + r;
        if (rr < c) {
          float l = acc[i][j][r];
          int bit = rr * N + c;
          bool a = (adjg[bit >> 5] >> (bit & 31)) & 1u;
          float spabs = log1pf(expf(-fabsf(l)));
          if (a) spos += fmaxf(-l, 0.f) + spabs;
          else sneg += fmaxf(l, 0.f) + spabs;
        }
      }
    }
  for (int off = 32; off; off >>= 1) {
    spos += __shfl_down(spos, off);
    sneg += __shfl_down(sneg, off);
  }
  __shared__ float wp[4], wn[4];
  if ((tid & 63) == 0) { wp[tid >> 6] = spos; wn[tid >> 6] = sneg; }
  __syncthreads();
  if (tid == 0) {
    atomicAdd(&Spos[g], wp[0] + wp[1] + wp[2] + wp[3]);
    atomicAdd(&Sneg[g], wn[0] + wn[1] + wn[2] + wn[3]);
  }
}

// ---------------- finalize ----------------
__global__ void __launch_bounds__(256) k_final(
    const int* __restrict__ nedge, const float* __restrict__ Spos,
    const float* __restrict__ Sneg, const float* __restrict__ vq_part,
    float* __restrict__ out) {
  int t = threadIdx.x;  // 256
  float vq = 0.f;
  for (int i = t; i < GN; i += 256) vq += vq_part[i];
  float el = 0.f;
  if (t < G) {
    float ne = (float)nedge[t];
    float pw = (131072.0f - ne) / (ne + 1e-6f);          // N*N/2
    el = (pw * Spos[t] + Sneg[t]) * (1.0f / 130816.0f);  // N*(N-1)/2
  }
  for (int off = 32; off; off >>= 1) {
    vq += __shfl_down(vq, off);
    el += __shfl_down(el, off);
  }
  __shared__ float wv[4], we[4];
  if ((t & 63) == 0) { wv[t >> 6] = vq; we[t >> 6] = el; }
  __syncthreads();
  if (t == 0) {
    float vqs = wv[0] + wv[1] + wv[2] + wv[3];
    float els = we[0] + we[1] + we[2] + we[3];
    out[0] = 100.0f * (els * (1.0f / G)) + 1000.0f * (vqs * (1.0f / ((float)GN * D)));
  }
}

extern "C" void kernel_launch(void* const* d_in, const int* in_sizes, int n_in,
                              void* d_out, int out_size, void* d_ws, size_t ws_size,
                              hipStream_t stream) {
  const float* feats = (const float*)d_in[0];
  const int* src = (const int*)d_in[1];
  const int* dst = (const int*)d_in[2];
  const float* W1 = (const float*)d_in[3];
  const float* b1 = (const float*)d_in[4];
  const float* W2 = (const float*)d_in[5];
  const float* b2 = (const float*)d_in[6];
  const float* ln_g = (const float*)d_in[7];
  const float* ln_b = (const float*)d_in[8];
  const float* dec1_W = (const float*)d_in[9];
  const float* dec1_b = (const float*)d_in[10];
  // d_in[11], d_in[12] = dec2 (unused: LAMB_NODE == 0)
  const float* cb = (const float*)d_in[13];

  char* ws = (char*)d_ws;
  float* Spos = (float*)(ws + OFF_SPOS);
  float* Sneg = (float*)(ws + OFF_SNEG);
  unsigned long long* best = (unsigned long long*)(ws + OFF_BEST);
  int* nedge = (int*)(ws + OFF_NEDGE);
  float* vq_part = (float*)(ws + OFF_VQPART);
  int* row_off = (int*)(ws + OFF_ROWOFF);
  float* rs_out = (float*)(ws + OFF_RS_OUT);
  float* rs_in = (float*)(ws + OFF_RS_IN);
  int* deg_in = (int*)(ws + OFF_DEG_IN);
  int* csr_src = (int*)(ws + OFF_CSR);
  unsigned* adj = (unsigned*)(ws + OFF_ADJ);
  float* rnc = (float*)(ws + OFF_RNC);
  __bf16* W1t = (__bf16*)(ws + OFF_W1T);
  __bf16* W2t = (__bf16*)(ws + OFF_W2T);
  __bf16* dWt = (__bf16*)(ws + OFF_DWT);
  __bf16* cbb = (__bf16*)(ws + OFF_CBB);
  unsigned* featsb2 = (unsigned*)(ws + OFF_FEB);
  __bf16* aggb = (__bf16*)(ws + OFF_AGGB);   // agg out (conv A); later qe
  unsigned* aggb2 = (unsigned*)(ws + OFF_AGGB);
  float* bf32 = (float*)(ws + OFF_BF32);     // hf fp32
  __bf16* bcb = (__bf16*)(ws + OFF_BCB);     // h1 (LN in place), then hf bf16
  unsigned* bcb2 = (unsigned*)(ws + OFF_BCB);

  hipMemsetAsync(d_ws, 0, ZERO_BYTES, stream);  // Spos/Sneg/best (~131 KB)

  // setup: graph build + weight transpose + codebook + feats cast, one launch
  k_setup<<<2272, 512, 0, stream>>>(src, dst, adj, nedge, row_off, rs_in, rs_out,
                                    deg_in, csr_src, W1, W2, dec1_W, W1t, W2t, dWt,
                                    cb, cbb, rnc, feats, featsb2);

  // conv1: aggregate(bf16) -> MFMA GEMM(relu, bf16 out) -> layernorm(bf16 in place)
  k_aggregate<<<GN, 128, 0, stream>>>(featsb2, csr_src, row_off, deg_in, rs_in, rs_out,
                                      aggb2);
  k_gemm_bf16<true, false, true><<<dim3(GN / 128, 2), 256, 0, stream>>>(
      aggb, W1t, b1, nullptr, bcb);
  k_layernorm<<<GN, 128, 0, stream>>>(bcb2, ln_g, ln_b);

  // conv2: aggregate(bf16) -> MFMA GEMM(relu, dual store: hf fp32 + bf16)
  k_aggregate<<<GN, 128, 0, stream>>>(bcb2, csr_src, row_off, deg_in, rs_in, rs_out, aggb2);
  k_gemm_bf16<true, true, true><<<dim3(GN / 128, 2), 256, 0, stream>>>(
      aggb, W2t, b2, bf32, bcb);

  // VQ argmax (r9 high-occupancy form); dec1 gathers q + fused vq error
  k_vq_bf16<<<dim3(GN / 128, KCB / 128), 256, 0, stream>>>(bcb, cbb, rnc, best);
  k_gemm_dec1<<<dim3(GN / 128, 2), 256, 0, stream>>>(cbb, best, dWt, dec1_b, aggb,
                                                     cb, bf32, vq_part);
  k_edge_bf16<<<10 * G, 256, 0, stream>>>(aggb, adj, Spos, Sneg);

  k_final<<<1, 256, 0, stream>>>(nedge, Spos, Sneg, vq_part, (float*)d_out);
}

// Round 12
// 265.538 us; speedup vs baseline: 1.0636x; 1.0437x over previous
//
#include <hip/hip_runtime.h>
#include <math.h>

#define G 32
#define N 512
#define E 8192
#define D 256
#define KCB 2048
#define GN (G * N)  // 16384

typedef __bf16 bf16x8 __attribute__((ext_vector_type(8)));
typedef float f32x4 __attribute__((ext_vector_type(4)));

// ---------------- ws layout (bytes), all offsets 256-aligned (r7/r9 layout) ----------------
static const size_t OFF_SPOS   = 0;                                   // float [G]
static const size_t OFF_SNEG   = OFF_SPOS + 256;                      // float [G]
static const size_t OFF_BEST   = OFF_SNEG + 256;                      // u64 [GN]
static const size_t ZERO_BYTES = OFF_BEST + (size_t)GN * 8;           // ~131 KB
static const size_t OFF_NEDGE  = ZERO_BYTES;                          // int [G]
static const size_t OFF_VQPART = OFF_NEDGE + 256;                     // float [GN]
static const size_t OFF_ROWOFF = OFF_VQPART + (size_t)GN * 4;         // int [GN]
static const size_t OFF_RS_OUT = OFF_ROWOFF + (size_t)GN * 4;         // float [GN]
static const size_t OFF_RS_IN  = OFF_RS_OUT + (size_t)GN * 4;         // float [GN]
static const size_t OFF_DEG_IN = OFF_RS_IN + (size_t)GN * 4;          // int [GN]
static const size_t OFF_CSR    = OFF_DEG_IN + (size_t)GN * 4;         // int [G*E]
static const size_t OFF_ADJ    = OFF_CSR + (size_t)G * E * 4;         // uint [G*N*N/32]
static const size_t OFF_RNC    = OFF_ADJ + (size_t)G * N * N / 8;     // float [KCB]
static const size_t OFF_W1T    = OFF_RNC + (size_t)KCB * 4;           // bf16 [D*D]
static const size_t OFF_W2T    = OFF_W1T + (size_t)D * D * 2;         // bf16 [D*D]
static const size_t OFF_DWT    = OFF_W2T + (size_t)D * D * 2;         // bf16 [D*D]
static const size_t OFF_CBB    = OFF_DWT + (size_t)D * D * 2;         // bf16 [KCB*D]
static const size_t OFF_FEB    = OFF_CBB + (size_t)KCB * D * 2;       // bf16 [GN*D]
static const size_t OFF_AGGB   = OFF_FEB + (size_t)GN * D * 2;        // bf16 [GN*D]
static const size_t OFF_BF32   = OFF_AGGB + (size_t)GN * D * 2;       // float [GN*D] hf
static const size_t OFF_BCB    = OFF_BF32 + (size_t)GN * D * 4;       // bf16 [GN*D]

// ---------------- mega-setup: graph build (0..31) + W transpose (32..223) ----------------
// + codebook cast/norm (224..1247, 2 rows/block) + feats cast (1248..2271).
__global__ void __launch_bounds__(512) k_setup(
    const int* __restrict__ src, const int* __restrict__ dst,
    unsigned* __restrict__ adj, int* __restrict__ nedge, int* __restrict__ row_off_g,
    float* __restrict__ rs_in_g, float* __restrict__ rs_out_g,
    int* __restrict__ deg_in_g, int* __restrict__ csr_src,
    const float* __restrict__ W1, const float* __restrict__ W2,
    const float* __restrict__ dW, __bf16* __restrict__ W1t,
    __bf16* __restrict__ W2t, __bf16* __restrict__ dWt,
    const float* __restrict__ cb, __bf16* __restrict__ cbb, float* __restrict__ rnc,
    const float* __restrict__ feats, unsigned* __restrict__ featsb2) {
  __shared__ __align__(16) char smem[41088];
  int b = blockIdx.x, t = threadIdx.x;
  if (b < 32) {  // -------- graph build (one block per graph; LDS-local atomics) --------
    int g = b;
    unsigned* s_adj = (unsigned*)smem;                 // 32768 B
    int* s_deg_in = (int*)(smem + 32768);              // 2048 B
    int* s_deg_out = (int*)(smem + 34816);             // 2048 B
    int(*s_buf)[N] = (int(*)[N])(smem + 36864);        // 4096 B
    int* s_red = (int*)(smem + 40960);                 // 32 B
    for (int i = t; i < N * N / 32; i += 512) s_adj[i] = 0;
    s_deg_in[t] = 0;
    s_deg_out[t] = 0;
    __syncthreads();
    const int* sg = src + g * E;
    const int* dg = dst + g * E;
    int se[E / 512], de[E / 512];
    int ecount = 0;
#pragma unroll
    for (int j = 0; j < E / 512; ++j) {
      int s = sg[t + j * 512], d = dg[t + j * 512];
      se[j] = s; de[j] = d;
      atomicAdd(&s_deg_out[s], 1);
      atomicAdd(&s_deg_in[d], 1);
      if (s < d) {
        int bit = s * N + d;
        unsigned m = 1u << (bit & 31);
        unsigned old = atomicOr(&s_adj[bit >> 5], m);
        if (!(old & m)) ++ecount;
      }
    }
    __syncthreads();
    for (int off = 32; off; off >>= 1) ecount += __shfl_down(ecount, off);
    if ((t & 63) == 0) s_red[t >> 6] = ecount;
    __syncthreads();
    if (t == 0) {
      int tot = 0;
      for (int i = 0; i < 8; ++i) tot += s_red[i];
      nedge[g] = tot;
    }
    unsigned* adjg = adj + (size_t)g * (N * N / 32);
    for (int i = t; i < N * N / 32; i += 512) adjg[i] = s_adj[i];
    int own = s_deg_in[t];
    s_buf[0][t] = own;
    __syncthreads();
    int cur = 0;
    for (int off = 1; off < N; off <<= 1) {
      int v = s_buf[cur][t];
      if (t >= off) v += s_buf[cur][t - off];
      s_buf[cur ^ 1][t] = v;
      __syncthreads();
      cur ^= 1;
    }
    int roff = s_buf[cur][t] - own;
    row_off_g[g * N + t] = roff;
    deg_in_g[g * N + t] = own;
    rs_in_g[g * N + t] = rsqrtf(fmaxf((float)own, 1.0f));
    rs_out_g[g * N + t] = rsqrtf(fmaxf((float)s_deg_out[t], 1.0f));
    __syncthreads();
    s_deg_in[t] = roff;  // reuse as scatter cursor
    __syncthreads();
    int* csrg = csr_src + g * E;
#pragma unroll
    for (int j = 0; j < E / 512; ++j) {
      int slot = atomicAdd(&s_deg_in[de[j]], 1);
      csrg[slot] = se[j];
    }
  } else if (b < 224) {  // -------- weight transpose: 3 matrices x 64 32x32 tiles --------
    float(*tile)[33] = (float(*)[33])smem;
    int z = (b - 32) / 64, tt = (b - 32) % 64;
    int bx = (tt & 7) * 32, by = (tt >> 3) * 32;
    const float* in = z == 0 ? W1 : (z == 1 ? W2 : dW);
    __bf16* out = z == 0 ? W1t : (z == 1 ? W2t : dWt);
    int tx = t & 31, ty = t >> 5;  // 32 x 16
#pragma unroll
    for (int r = 0; r < 32; r += 16) tile[ty + r][tx] = in[(by + ty + r) * D + bx + tx];
    __syncthreads();
#pragma unroll
    for (int r = 0; r < 32; r += 16)
      out[(size_t)(bx + ty + r) * D + by + tx] = (__bf16)tile[tx][ty + r];
  } else if (b < 1248) {  // -------- codebook cast + inv-norms, 2 rows per block --------
    float* w = (float*)smem;  // [8]
    int row = (b - 224) * 2 + (t >> 8);
    int col = t & 255;
    float v = cb[(size_t)row * D + col];
    cbb[(size_t)row * D + col] = (__bf16)v;
    float s2 = v * v;
    for (int off = 32; off; off >>= 1) s2 += __shfl_down(s2, off);
    if ((t & 63) == 0) w[t >> 6] = s2;
    __syncthreads();
    if (t == 0) rnc[row] = rsqrtf(w[0] + w[1] + w[2] + w[3] + 1e-12f);
    if (t == 256) rnc[row] = rsqrtf(w[4] + w[5] + w[6] + w[7] + 1e-12f);
  } else {  // -------- feats fp32 -> bf16 pairs: 1024 blocks x 512 thr x 4 words --------
    int i0 = (b - 1248) * 2048 + t;
#pragma unroll
    for (int q = 0; q < 4; ++q) {
      int i = i0 + q * 512;
      float2 v = ((const float2*)feats)[i];
      union { __bf16 h[2]; unsigned u; } o;
      o.h[0] = (__bf16)v.x;
      o.h[1] = (__bf16)v.y;
      featsb2[i] = o.u;
    }
  }
}

// ---------------- graph-conv aggregation: bf16 in/out, XCD-swizzled, LDS idx preload --------
__global__ void __launch_bounds__(128) k_aggregate(
    const unsigned* __restrict__ x2, const int* __restrict__ csr_src,
    const int* __restrict__ row_off, const int* __restrict__ deg_in,
    const float* __restrict__ rs_in, const float* __restrict__ rs_out,
    unsigned* __restrict__ out2) {
  int b = blockIdx.x;
  int g = ((b & 7) << 2) | (b >> 12);  // (b&7)*4 + (b>>3)/512
  int n = (b >> 3) & 511;
  int gn = (g << 9) | n;
  int t = threadIdx.x;  // 128 feature-pairs
  int cnt = deg_in[gn];
  int base = g * E + row_off[gn];
  __shared__ int sidx[128];
  __shared__ float sw[128];
  float ax = 0.f, ay = 0.f;
  for (int c0 = 0; c0 < cnt; c0 += 128) {
    int m = min(128, cnt - c0);
    if (t < m) {
      int s = csr_src[base + c0 + t];
      sidx[t] = s;
      sw[t] = rs_out[(g << 9) | s];
    }
    __syncthreads();
    for (int j = 0; j < m; ++j) {
      int s = sidx[j];
      float w = sw[j];
      unsigned v = x2[((size_t)((g << 9) | s) << 7) + t];
      ax += __uint_as_float(v << 16) * w;
      ay += __uint_as_float(v & 0xffff0000u) * w;
    }
    __syncthreads();
  }
  float ri = rs_in[gn];
  union { __bf16 h[2]; unsigned u; } o;
  o.h[0] = (__bf16)(ax * ri);
  o.h[1] = (__bf16)(ay * ri);
  out2[((size_t)gn << 7) + t] = o.u;
}

// ---------------- bf16 MFMA core: 128x128 tile, K=256, stride 256, BT layout ----------------
__device__ __forceinline__ void gload_lds16(const __bf16* g, __bf16* s) {
  __builtin_amdgcn_global_load_lds((const __attribute__((address_space(1))) void*)g,
                                   (__attribute__((address_space(3))) void*)s, 16, 0, 0);
}

__device__ __forceinline__ void mfma_core(const __bf16* __restrict__ Abase,
                                          const __bf16* __restrict__ Bbase,
                                          __bf16* sA, __bf16* sB, f32x4 (&acc)[4][4],
                                          int tid) {
  int wave = tid >> 6, lane = tid & 63;
  int wr = (wave >> 1) * 64, wc = (wave & 1) * 64;
  int m = lane & 15, quad = lane >> 4;
  for (int k0 = 0; k0 < 256; k0 += 32) {
#pragma unroll
    for (int c2 = 0; c2 < 2; ++c2) {
      int c = wave * 2 + c2;
      int row = c * 16 + (lane >> 2);
      int col = (lane & 3) * 8;
      gload_lds16(Abase + (size_t)row * 256 + k0 + col, sA + c * 512);
      gload_lds16(Bbase + (size_t)row * 256 + k0 + col, sB + c * 512);
    }
    __syncthreads();
    bf16x8 af[4], bfr[4];
#pragma unroll
    for (int i = 0; i < 4; ++i) {
      af[i] = *(const bf16x8*)&sA[(wr + i * 16 + m) * 32 + quad * 8];
      bfr[i] = *(const bf16x8*)&sB[(wc + i * 16 + m) * 32 + quad * 8];
    }
#pragma unroll
    for (int i = 0; i < 4; ++i)
#pragma unroll
      for (int j = 0; j < 4; ++j)
        acc[i][j] = __builtin_amdgcn_mfma_f32_16x16x32_bf16(af[i], bfr[j], acc[i][j], 0, 0, 0);
    __syncthreads();
  }
}

// ---------------- GEMM + bias (+relu), fp32/bf16 stores, Ncols=256 ----------------
template <bool RELU, bool SF32, bool SBF16>
__global__ void __launch_bounds__(256) k_gemm_bf16(
    const __bf16* __restrict__ A, const __bf16* __restrict__ Bt,
    const float* __restrict__ bias, float* __restrict__ C, __bf16* __restrict__ Cb) {
  __shared__ __align__(16) __bf16 sA[4096], sB[4096];
  f32x4 acc[4][4] = {};
  int tid = threadIdx.x;
  int row0 = blockIdx.x * 128, col0 = blockIdx.y * 128;
  mfma_core(A + (size_t)row0 * 256, Bt + (size_t)col0 * 256, sA, sB, acc, tid);
  int wave = tid >> 6, lane = tid & 63;
  int wr = (wave >> 1) * 64, wc = (wave & 1) * 64, quad = lane >> 4, n16 = lane & 15;
#pragma unroll
  for (int j = 0; j < 4; ++j) {
    int col = col0 + wc + j * 16 + n16;
    float bs = bias[col];
#pragma unroll
    for (int i = 0; i < 4; ++i)
#pragma unroll
      for (int r = 0; r < 4; ++r) {
        int row = row0 + wr + i * 16 + quad * 4 + r;  // C/D: col=lane&15, row=quad*4+reg
        float v = acc[i][j][r] + bs;
        if (RELU) v = fmaxf(v, 0.f);
        if (SF32) C[(size_t)row * 256 + col] = v;
        if (SBF16) Cb[(size_t)row * 256 + col] = (__bf16)v;
      }
  }
}

// ---------------- dec1 GEMM with gathered A: q[row] = cbb[best[row]] (no q buffer) --------
__global__ void __launch_bounds__(256) k_gemm_dec1(
    const __bf16* __restrict__ cbb, const unsigned long long* __restrict__ best,
    const __bf16* __restrict__ Bt, const float* __restrict__ bias,
    __bf16* __restrict__ Cb) {
  __shared__ __align__(16) __bf16 sA[4096], sB[4096];
  f32x4 acc[4][4] = {};
  int tid = threadIdx.x, wave = tid >> 6, lane = tid & 63;
  int row0 = blockIdx.x * 128, col0 = blockIdx.y * 128;
  int wr = (wave >> 1) * 64, wc = (wave & 1) * 64;
  int m = lane & 15, quad = lane >> 4;
  // per-lane codebook row indices for this wave's 2 A-staging chunks (k0-invariant)
  int c0 = wave * 2, c1 = wave * 2 + 1;
  int idx0 = (int)(0xFFFFFFFFu -
                   (unsigned)(best[row0 + c0 * 16 + (lane >> 2)] & 0xFFFFFFFFull));
  int idx1 = (int)(0xFFFFFFFFu -
                   (unsigned)(best[row0 + c1 * 16 + (lane >> 2)] & 0xFFFFFFFFull));
  const __bf16* Bbase = Bt + (size_t)col0 * 256;
  for (int k0 = 0; k0 < 256; k0 += 32) {
    int col = (lane & 3) * 8;
    gload_lds16(cbb + (size_t)idx0 * 256 + k0 + col, sA + c0 * 512);
    gload_lds16(cbb + (size_t)idx1 * 256 + k0 + col, sA + c1 * 512);
    gload_lds16(Bbase + (size_t)(c0 * 16 + (lane >> 2)) * 256 + k0 + col, sB + c0 * 512);
    gload_lds16(Bbase + (size_t)(c1 * 16 + (lane >> 2)) * 256 + k0 + col, sB + c1 * 512);
    __syncthreads();
    bf16x8 af[4], bfr[4];
#pragma unroll
    for (int i = 0; i < 4; ++i) {
      af[i] = *(const bf16x8*)&sA[(wr + i * 16 + m) * 32 + quad * 8];
      bfr[i] = *(const bf16x8*)&sB[(wc + i * 16 + m) * 32 + quad * 8];
    }
#pragma unroll
    for (int i = 0; i < 4; ++i)
#pragma unroll
      for (int j = 0; j < 4; ++j)
        acc[i][j] = __builtin_amdgcn_mfma_f32_16x16x32_bf16(af[i], bfr[j], acc[i][j], 0, 0, 0);
    __syncthreads();
  }
  int n16 = lane & 15;
#pragma unroll
  for (int j = 0; j < 4; ++j) {
    int col = col0 + wc + j * 16 + n16;
    float bs = bias[col];
#pragma unroll
    for (int i = 0; i < 4; ++i)
#pragma unroll
      for (int r = 0; r < 4; ++r) {
        int row = row0 + wr + i * 16 + quad * 4 + r;
        Cb[(size_t)row * 256 + col] = (__bf16)(acc[i][j][r] + bs);
      }
  }
}

// ---------------- LayerNorm: bf16 pairs in place ----------------
__global__ void __launch_bounds__(128) k_layernorm(
    unsigned* __restrict__ xb2, const float* __restrict__ gamma,
    const float* __restrict__ beta) {
  int row = blockIdx.x, t = threadIdx.x;  // 128 feature-pairs
  unsigned u = xb2[row * 128 + t];
  float vx = __uint_as_float(u << 16), vy = __uint_as_float(u & 0xffff0000u);
  float s = vx + vy, s2 = vx * vx + vy * vy;
  for (int off = 32; off; off >>= 1) {
    s += __shfl_down(s, off);
    s2 += __shfl_down(s2, off);
  }
  __shared__ float w1[2], w2[2];
  if ((t & 63) == 0) { w1[t >> 6] = s; w2[t >> 6] = s2; }
  __syncthreads();
  float mu = (w1[0] + w1[1]) * (1.f / D);
  float m2 = (w2[0] + w2[1]) * (1.f / D);
  float rstd = rsqrtf(m2 - mu * mu + 1e-5f);
  float2 gm = ((const float2*)gamma)[t];
  float2 bt = ((const float2*)beta)[t];
  union { __bf16 h[2]; unsigned u; } o;
  o.h[0] = (__bf16)((vx - mu) * rstd * gm.x + bt.x);
  o.h[1] = (__bf16)((vy - mu) * rstd * gm.y + bt.y);
  xb2[row * 128 + t] = o.u;
}

// ---------------- VQ: bf16 MFMA sims + packed argmax (high-occupancy r9 form) ----------
__global__ void __launch_bounds__(256) k_vq_bf16(
    const __bf16* __restrict__ A, const __bf16* __restrict__ CBt,
    const float* __restrict__ rnc, unsigned long long* __restrict__ best) {
  __shared__ __align__(16) __bf16 sA[4096], sB[4096];
  f32x4 acc[4][4] = {};
  int tid = threadIdx.x;
  int row0 = blockIdx.x * 128, col0 = blockIdx.y * 128;
  mfma_core(A + (size_t)row0 * 256, CBt + (size_t)col0 * 256, sA, sB, acc, tid);
  int wave = tid >> 6, lane = tid & 63;
  int wr = (wave >> 1) * 64, wc = (wave & 1) * 64, quad = lane >> 4, n16 = lane & 15;
#pragma unroll
  for (int i = 0; i < 4; ++i) {
    unsigned long long cand[4] = {0ull, 0ull, 0ull, 0ull};
#pragma unroll
    for (int j = 0; j < 4; ++j) {
      int col = col0 + wc + j * 16 + n16;
      float rc = rnc[col];
#pragma unroll
      for (int r = 0; r < 4; ++r) {
        float sim = acc[i][j][r] * rc;
        unsigned u = __float_as_uint(sim);
        u = ((int)u >= 0) ? (u | 0x80000000u) : ~u;  // order-preserving map
        unsigned long long c64 =
            ((unsigned long long)u << 32) | (0xFFFFFFFFu - (unsigned)col);
        cand[r] = cand[r] > c64 ? cand[r] : c64;
      }
    }
#pragma unroll
    for (int off = 1; off < 16; off <<= 1)
#pragma unroll
      for (int r = 0; r < 4; ++r) {
        unsigned long long o = __shfl_xor(cand[r], off, 64);
        cand[r] = cand[r] > o ? cand[r] : o;
      }
    if (n16 == 0)
#pragma unroll
      for (int r = 0; r < 4; ++r)
        atomicMax(&best[row0 + wr + i * 16 + quad * 4 + r], cand[r]);
  }
}

// ---------------- vq error only (separate kernel — r11 fusion into dec1 regressed) --------
__global__ void k_vq_err(const unsigned long long* __restrict__ best,
                         const float* __restrict__ cb, const float* __restrict__ hf,
                         float* __restrict__ vq_part) {
  int row = blockIdx.x, t = threadIdx.x;  // 256
  unsigned long long b = best[row];
  int c = (int)(0xFFFFFFFFu - (unsigned)(b & 0xFFFFFFFFull));
  float d = cb[(size_t)c * D + t] - hf[(size_t)row * D + t];
  float s2 = d * d;
  for (int off = 32; off; off >>= 1) s2 += __shfl_down(s2, off);
  __shared__ float w[4];
  if ((t & 63) == 0) w[t >> 6] = s2;
  __syncthreads();
  if (t == 0) vq_part[row] = w[0] + w[1] + w[2] + w[3];
}

// ---------------- edge loss: per-graph qe qe^T upper tiles, bf16 MFMA + softplus ----------
__constant__ int c_ti[10] = {0, 0, 0, 0, 1, 1, 1, 2, 2, 3};
__constant__ int c_tj[10] = {0, 1, 2, 3, 1, 2, 3, 2, 3, 3};

__global__ void __launch_bounds__(256) k_edge_bf16(
    const __bf16* __restrict__ qe, const unsigned* __restrict__ adj,
    float* __restrict__ Spos, float* __restrict__ Sneg) {
  int g = blockIdx.x / 10, p = blockIdx.x % 10;
  int row0 = c_ti[p] * 128, col0 = c_tj[p] * 128;
  const __bf16* Ag = qe + (size_t)g * N * D;
  const unsigned* adjg = adj + (size_t)g * (N * N / 32);
  __shared__ __align__(16) __bf16 sA[4096], sB[4096];
  f32x4 acc[4][4] = {};
  int tid = threadIdx.x;
  mfma_core(Ag + (size_t)row0 * 256, Ag + (size_t)col0 * 256, sA, sB, acc, tid);
  int wave = tid >> 6, lane = tid & 63;
  int wr = (wave >> 1) * 64, wc = (wave & 1) * 64, quad = lane >> 4, n16 = lane & 15;
  float spos = 0.f, sneg = 0.f;
#pragma unroll
  for (int i = 0; i < 4; ++i)
#pragma unroll
    for (int j = 0; j < 4; ++j) {
      int c = col0 + wc + j * 16 + n16;
#pragma unroll
      for (int r = 0; r < 4; ++r) {
        int rr = row0 + wr + i * 16 + quad * 4 + r;
        if (rr < c) {
          float l = acc[i][j][r];
          int bit = rr * N + c;
          bool a = (adjg[bit >> 5] >> (bit & 31)) & 1u;
          float spabs = log1pf(expf(-fabsf(l)));
          if (a) spos += fmaxf(-l, 0.f) + spabs;
          else sneg += fmaxf(l, 0.f) + spabs;
        }
      }
    }
  for (int off = 32; off; off >>= 1) {
    spos += __shfl_down(spos, off);
    sneg += __shfl_down(sneg, off);
  }
  __shared__ float wp[4], wn[4];
  if ((tid & 63) == 0) { wp[tid >> 6] = spos; wn[tid >> 6] = sneg; }
  __syncthreads();
  if (tid == 0) {
    atomicAdd(&Spos[g], wp[0] + wp[1] + wp[2] + wp[3]);
    atomicAdd(&Sneg[g], wn[0] + wn[1] + wn[2] + wn[3]);
  }
}

// ---------------- finalize ----------------
__global__ void __launch_bounds__(256) k_final(
    const int* __restrict__ nedge, const float* __restrict__ Spos,
    const float* __restrict__ Sneg, const float* __restrict__ vq_part,
    float* __restrict__ out) {
  int t = threadIdx.x;  // 256
  float vq = 0.f;
  for (int i = t; i < GN; i += 256) vq += vq_part[i];
  float el = 0.f;
  if (t < G) {
    float ne = (float)nedge[t];
    float pw = (131072.0f - ne) / (ne + 1e-6f);          // N*N/2
    el = (pw * Spos[t] + Sneg[t]) * (1.0f / 130816.0f);  // N*(N-1)/2
  }
  for (int off = 32; off; off >>= 1) {
    vq += __shfl_down(vq, off);
    el += __shfl_down(el, off);
  }
  __shared__ float wv[4], we[4];
  if ((t & 63) == 0) { wv[t >> 6] = vq; we[t >> 6] = el; }
  __syncthreads();
  if (t == 0) {
    float vqs = wv[0] + wv[1] + wv[2] + wv[3];
    float els = we[0] + we[1] + we[2] + we[3];
    out[0] = 100.0f * (els * (1.0f / G)) + 1000.0f * (vqs * (1.0f / ((float)GN * D)));
  }
}

extern "C" void kernel_launch(void* const* d_in, const int* in_sizes, int n_in,
                              void* d_out, int out_size, void* d_ws, size_t ws_size,
                              hipStream_t stream) {
  const float* feats = (const float*)d_in[0];
  const int* src = (const int*)d_in[1];
  const int* dst = (const int*)d_in[2];
  const float* W1 = (const float*)d_in[3];
  const float* b1 = (const float*)d_in[4];
  const float* W2 = (const float*)d_in[5];
  const float* b2 = (const float*)d_in[6];
  const float* ln_g = (const float*)d_in[7];
  const float* ln_b = (const float*)d_in[8];
  const float* dec1_W = (const float*)d_in[9];
  const float* dec1_b = (const float*)d_in[10];
  // d_in[11], d_in[12] = dec2 (unused: LAMB_NODE == 0)
  const float* cb = (const float*)d_in[13];

  char* ws = (char*)d_ws;
  float* Spos = (float*)(ws + OFF_SPOS);
  float* Sneg = (float*)(ws + OFF_SNEG);
  unsigned long long* best = (unsigned long long*)(ws + OFF_BEST);
  int* nedge = (int*)(ws + OFF_NEDGE);
  float* vq_part = (float*)(ws + OFF_VQPART);
  int* row_off = (int*)(ws + OFF_ROWOFF);
  float* rs_out = (float*)(ws + OFF_RS_OUT);
  float* rs_in = (float*)(ws + OFF_RS_IN);
  int* deg_in = (int*)(ws + OFF_DEG_IN);
  int* csr_src = (int*)(ws + OFF_CSR);
  unsigned* adj = (unsigned*)(ws + OFF_ADJ);
  float* rnc = (float*)(ws + OFF_RNC);
  __bf16* W1t = (__bf16*)(ws + OFF_W1T);
  __bf16* W2t = (__bf16*)(ws + OFF_W2T);
  __bf16* dWt = (__bf16*)(ws + OFF_DWT);
  __bf16* cbb = (__bf16*)(ws + OFF_CBB);
  unsigned* featsb2 = (unsigned*)(ws + OFF_FEB);
  __bf16* aggb = (__bf16*)(ws + OFF_AGGB);   // agg out (conv A); later qe
  unsigned* aggb2 = (unsigned*)(ws + OFF_AGGB);
  float* bf32 = (float*)(ws + OFF_BF32);     // hf fp32
  __bf16* bcb = (__bf16*)(ws + OFF_BCB);     // h1 (LN in place), then hf bf16
  unsigned* bcb2 = (unsigned*)(ws + OFF_BCB);

  hipMemsetAsync(d_ws, 0, ZERO_BYTES, stream);  // Spos/Sneg/best (~131 KB)

  // setup: graph build + weight transpose + codebook + feats cast, one launch
  k_setup<<<2272, 512, 0, stream>>>(src, dst, adj, nedge, row_off, rs_in, rs_out,
                                    deg_in, csr_src, W1, W2, dec1_W, W1t, W2t, dWt,
                                    cb, cbb, rnc, feats, featsb2);

  // conv1: aggregate(bf16) -> MFMA GEMM(relu, bf16 out) -> layernorm(bf16 in place)
  k_aggregate<<<GN, 128, 0, stream>>>(featsb2, csr_src, row_off, deg_in, rs_in, rs_out,
                                      aggb2);
  k_gemm_bf16<true, false, true><<<dim3(GN / 128, 2), 256, 0, stream>>>(
      aggb, W1t, b1, nullptr, bcb);
  k_layernorm<<<GN, 128, 0, stream>>>(bcb2, ln_g, ln_b);

  // conv2: aggregate(bf16) -> MFMA GEMM(relu, dual store: hf fp32 + bf16)
  k_aggregate<<<GN, 128, 0, stream>>>(bcb2, csr_src, row_off, deg_in, rs_in, rs_out, aggb2);
  k_gemm_bf16<true, true, true><<<dim3(GN / 128, 2), 256, 0, stream>>>(
      aggb, W2t, b2, bf32, bcb);

  // VQ argmax; vq error from fp32 cb/hf; dec1 gathers q rows directly from cbb
  k_vq_bf16<<<dim3(GN / 128, KCB / 128), 256, 0, stream>>>(bcb, cbb, rnc, best);
  k_vq_err<<<GN, 256, 0, stream>>>(best, cb, bf32, vq_part);
  k_gemm_dec1<<<dim3(GN / 128, 2), 256, 0, stream>>>(cbb, best, dWt, dec1_b, aggb);
  k_edge_bf16<<<10 * G, 256, 0, stream>>>(aggb, adj, Spos, Sneg);

  k_final<<<1, 256, 0, stream>>>(nedge, Spos, Sneg, vq_part, (float*)d_out);
}